// Round 9
// baseline (2349.727 us; speedup 1.0000x reference)
//
#include <hip/hip_runtime.h>
#include <stdint.h>

#define NB 8
#define LL 128
#define NS 1928      // number of spans (l,r), r-l+1 <= 16
#define NK 10        // top-k
#define NK2 11       // tracked depth (detect boundary ties at 10/11)
#define WPB 4        // waves (spans) per block

// span id for (l, r): offset(l) + (r-l)
__device__ __forceinline__ int span_id(int l, int r) {
    int off = (l <= 112) ? (l << 4) : (NS - (((128 - l) * (129 - l)) >> 1));
    return off + (r - l);
}

// Replica of numpy's SIMD float32 exp (AVX512 runtime dispatch path).
__device__ __forceinline__ float npexp_f32(float x) {
    const float magic = 12582912.0f;
    const float log2e = 1.442695040888963f;
    const float c1 = -6.93145752e-1f;
    const float c2 = -1.42860677e-6f;
    float t = __fmul_rn(x, log2e);
    float q = __fsub_rn(__fadd_rn(t, magic), magic);
    float r = __fmaf_rn(q, c1, x);
    r = __fmaf_rn(q, c2, r);
    float num = __fmaf_rn(r, 5.082762527590693718096e-04f, 6.757896990527504603057e-03f);
    num = __fmaf_rn(num, r, 5.114512081637298353406e-02f);
    num = __fmaf_rn(num, r, 2.473615434895520810817e-01f);
    num = __fmaf_rn(num, r, 7.257664613233124478488e-01f);
    num = __fmaf_rn(num, r, 9.999999999980870924916e-01f);
    float den = __fmaf_rn(r, 2.159509375685829852307e-02f, -2.742335390411667452936e-01f);
    den = __fmaf_rn(den, r, 1.0f);
    float p = __fdiv_rn(num, den);
    int qi = (int)q;
    return __fmul_rn(p, __int_as_float((127 + qi) << 23));
}

__device__ __forceinline__ float keyval(unsigned long long k) {
    return __uint_as_float((unsigned)(k >> 32));
}

// Bit-faithful emulation of numpy aquicksort_float (argsort kind='quicksort'):
// packed keys hi32=float bits, lo32=original index; compares VALUE ONLY
// (equal values' order = introsort scramble, exactly as numpy). Includes
// median-of-3, Hoare-ish partition, SMALL_QUICKSORT=15 insertion leaves,
// depth_limit=2*msb(n) with aheapsort fallback. Sequential (call on 1 lane).
__device__ void np_introsort(unsigned long long* a, int n) {
    int depth = 0; { int v = n; while (v >>= 1) ++depth; }
    depth *= 2;
    int stack[64]; int sp = 0;
    int lo = 0, hi = n - 1;
    unsigned long long t, vi, tmp;
    int mid, pi, pj, pk, i2, j2, hl, hm, hi_, hj;
    float vp;
    for (;;) {
        while (hi - lo > 15) {
            if (depth-- < 0) {
                // aheapsort on [lo,hi] (1-based h[])
                unsigned long long* h = a + lo - 1;
                hm = hi - lo + 1;
                for (hl = hm >> 1; hl > 0; --hl) {
                    tmp = h[hl];
                    hi_ = hl; hj = hl * 2;
                    while (hj <= hm) {
                        if (hj < hm && keyval(h[hj]) < keyval(h[hj + 1])) ++hj;
                        if (keyval(tmp) < keyval(h[hj])) { h[hi_] = h[hj]; hi_ = hj; hj += hj; }
                        else break;
                    }
                    h[hi_] = tmp;
                }
                while (hm > 1) {
                    tmp = h[hm]; h[hm] = h[1]; --hm;
                    hi_ = 1; hj = 2;
                    while (hj <= hm) {
                        if (hj < hm && keyval(h[hj]) < keyval(h[hj + 1])) ++hj;
                        if (keyval(tmp) < keyval(h[hj])) { h[hi_] = h[hj]; hi_ = hj; hj += hj; }
                        else break;
                    }
                    h[hi_] = tmp;
                }
                goto pop;
            }
            mid = lo + ((hi - lo) >> 1);
            if (keyval(a[mid]) < keyval(a[lo])) { t = a[mid]; a[mid] = a[lo]; a[lo] = t; }
            if (keyval(a[hi]) < keyval(a[mid])) { t = a[hi]; a[hi] = a[mid]; a[mid] = t; }
            if (keyval(a[mid]) < keyval(a[lo])) { t = a[mid]; a[mid] = a[lo]; a[lo] = t; }
            vp = keyval(a[mid]);
            pi = lo; pj = hi - 1;
            t = a[mid]; a[mid] = a[pj]; a[pj] = t;
            for (;;) {
                do { ++pi; } while (keyval(a[pi]) < vp);
                do { --pj; } while (vp < keyval(a[pj]));
                if (pi >= pj) break;
                t = a[pi]; a[pi] = a[pj]; a[pj] = t;
            }
            pk = hi - 1;
            t = a[pi]; a[pi] = a[pk]; a[pk] = t;
            if (pi - lo < hi - pi) { stack[sp++] = pi + 1; stack[sp++] = hi; hi = pi - 1; }
            else { stack[sp++] = lo; stack[sp++] = pi - 1; lo = pi + 1; }
        }
        for (i2 = lo + 1; i2 <= hi; ++i2) {
            vi = a[i2]; vp = keyval(vi);
            j2 = i2;
            while (j2 > lo && vp < keyval(a[j2 - 1])) { a[j2] = a[j2 - 1]; --j2; }
            a[j2] = vi;
        }
pop:
        if (sp == 0) break;
        hi = stack[--sp]; lo = stack[--sp];
    }
}

// Kernel 1: per (b,t) extract raw top1 head index, zero flags
__global__ void top1_kernel(const int* __restrict__ hi,
                            unsigned char* __restrict__ top1,
                            unsigned char* __restrict__ flags) {
    int tid = blockIdx.x * blockDim.x + threadIdx.x;
    if (tid >= NB * NS) return;
    int b = tid / NS, t = tid - b * NS;
    int l, r;
    if (t < 1808) { l = t >> 4; r = l + (t & 15); }
    else {
        l = 113;
        while (l < 127 && span_id(l + 1, l + 1) <= t) ++l;
        r = l + (t - span_id(l, l));
    }
    int i0 = hi[((b * LL + l) * LL + r) * 4];
    top1[b * NS + t] = (unsigned char)(i0 & 127);
    flags[b * NS + t] = 0;
}

// Kernel 2: one wave per (b,l) — cumsum cap: keep first 128 spans (t order) with top1==l
__global__ void cap_kernel(const unsigned char* __restrict__ top1,
                           unsigned char* __restrict__ flags) {
    int gw = (blockIdx.x * blockDim.x + threadIdx.x) >> 6;
    int lane = threadIdx.x & 63;
    int b = gw >> 7, l = gw & 127;
    const unsigned char* tb = top1 + b * NS;
    unsigned char* fb = flags + b * NS;
    int cnt = 0;
    for (int t0 = 0; t0 < NS; t0 += 64) {
        int t = t0 + lane;
        int tp = (t < NS) ? (int)tb[t] : 255;
        bool match = (tp == l);
        unsigned long long m = __ballot(match);
        if (match) {
            int pre = __popcll(m & ((1ull << lane) - 1ull));
            fb[t] = (cnt + pre + 1 <= 128) ? 1 : 0;
        }
        cnt += __popcll(m);
    }
}

// Kernel 3: main — one wave per span s; tie-aware with exact numpy-argsort slow path
__global__ __launch_bounds__(256)
void span_topk_kernel(const int* __restrict__ hi, const float* __restrict__ hw,
                      const float* __restrict__ dist,
                      const unsigned char* __restrict__ flags,
                      int* __restrict__ out) {
    __shared__ uint32_t s_rec[NS];
    __shared__ float s_W0[NS], s_W1[NS], s_W2[NS];
    __shared__ uint16_t s_lrc[NS];
    __shared__ float s_q[WPB][LL];
    __shared__ unsigned long long s_buf[NS];   // slow-path packed sort keys
    __shared__ int s_flag[WPB];

    const int b = blockIdx.y;
    const int* hb = hi + b * LL * LL * 4;
    const float* wb = hw + b * LL * LL * 4;
    const unsigned char* fb = flags + b * NS;

    // Stage 1: per-batch candidate table; heads sorted by index, duplicates combined in k-order
    for (int j = threadIdx.x; j < LL * 16; j += 256) {
        int l = j >> 4, w = j & 15, r = l + w;
        if (r < LL) {
            int sid = span_id(l, r);
            int4 iv = *(const int4*)(hb + (l * LL + r) * 4);
            float4 wv = *(const float4*)(wb + (l * LL + r) * 4);
            int ia = iv.x, ib = iv.y, ic = iv.z;
            float wa = wv.x, wb2 = wv.y, wc = wv.z;
            int m0, m1 = 255, m2 = 255;
            float W0, W1 = 0.f, W2 = 0.f;
            if (ia == ib && ib == ic) {
                m0 = ia; W0 = __fadd_rn(__fadd_rn(wa, wb2), wc);
            } else if (ia == ib) {
                float W = __fadd_rn(wa, wb2);
                if (ia < ic) { m0 = ia; W0 = W; m1 = ic; W1 = wc; }
                else         { m0 = ic; W0 = wc; m1 = ia; W1 = W; }
            } else if (ia == ic) {
                float W = __fadd_rn(wa, wc);
                if (ia < ib) { m0 = ia; W0 = W; m1 = ib; W1 = wb2; }
                else         { m0 = ib; W0 = wb2; m1 = ia; W1 = W; }
            } else if (ib == ic) {
                float W = __fadd_rn(wb2, wc);
                if (ia < ib) { m0 = ia; W0 = wa; m1 = ib; W1 = W; }
                else         { m0 = ib; W0 = W; m1 = ia; W1 = wa; }
            } else {
                int x0 = ia, x1 = ib, x2 = ic; float y0 = wa, y1 = wb2, y2 = wc;
                if (x0 > x1) { int tx = x0; x0 = x1; x1 = tx; float ty = y0; y0 = y1; y1 = ty; }
                if (x1 > x2) { int tx = x1; x1 = x2; x2 = tx; float ty = y1; y1 = y2; y2 = ty; }
                if (x0 > x1) { int tx = x0; x0 = x1; x1 = tx; float ty = y0; y0 = y1; y1 = ty; }
                m0 = x0; m1 = x1; m2 = x2; W0 = y0; W1 = y1; W2 = y2;
            }
            uint32_t cap = fb[sid] & 1u;
            s_rec[sid] = (uint32_t)m0 | ((uint32_t)m1 << 8) | ((uint32_t)m2 << 16)
                       | ((uint32_t)(ia & 127) << 24);
            s_W0[sid] = W0; s_W1[sid] = W1; s_W2[sid] = W2;
            s_lrc[sid] = (uint16_t)(l | (r << 7) | (cap << 14));
        }
    }
    __syncthreads();

    const int wid = threadIdx.x >> 6;
    const int lane = threadIdx.x & 63;
    const int s = blockIdx.x * WPB + wid;

    // Stage 2: q row (ascending-index FMA chain from 0) + coverage ballots
    uint32_t rec = s_rec[s];
    int m0 = rec & 255, m1 = (rec >> 8) & 255, m2 = (rec >> 16) & 255;
    bool e1 = (m1 != 255), e2 = (m2 != 255);
    float W0 = s_W0[s], W1 = s_W1[s], W2 = s_W2[s];
    uint32_t lrc = s_lrc[s];
    int ls = lrc & 127, rs = (lrc >> 7) & 127;

    const float* db = dist + b * LL * LL;
    const float* row0 = db + m0 * LL;
    const float* row1 = db + (e1 ? m1 : 0) * LL;
    const float* row2 = db + (e2 ? m2 : 0) * LL;
    int mA = lane, mB = lane + 64;
    float dA0 = row0[mA], dB0 = row0[mB];
    float dA1 = row1[mA], dB1 = row1[mB];
    float dA2 = row2[mA], dB2 = row2[mB];
    float qA = __fmaf_rn(W0, npexp_f32(-dA0), 0.0f);
    qA = __fmaf_rn(W1, npexp_f32(-dA1), qA);
    qA = __fmaf_rn(W2, npexp_f32(-dA2), qA);
    float qB = __fmaf_rn(W0, npexp_f32(-dB0), 0.0f);
    qB = __fmaf_rn(W1, npexp_f32(-dB1), qB);
    qB = __fmaf_rn(W2, npexp_f32(-dB2), qB);
    bool cA = (dA0 <= 2.0f || mA == m0) ||
              (e1 && (dA1 <= 2.0f || mA == m1)) ||
              (e2 && (dA2 <= 2.0f || mA == m2));
    bool cB = (dB0 <= 2.0f || mB == m0) ||
              (e1 && (dB1 <= 2.0f || mB == m1)) ||
              (e2 && (dB2 <= 2.0f || mB == m2));
    unsigned long long ub0 = __ballot(cA);
    unsigned long long ub1 = __ballot(cB);
    s_q[wid][mA] = qA;
    s_q[wid][mB] = qB;

    const float* q = s_q[wid];

    // shared gate+mask evaluator: used by BOTH fast scan and slow path (bit-identical)
    auto eval_gate = [&](int t, float& gate, bool& valid) {
        uint32_t rt = s_rec[t];
        int n0 = rt & 255, n1 = (rt >> 8) & 255, n2 = (rt >> 16) & 255, ri0 = rt >> 24;
        float g = __fmaf_rn(s_W0[t], q[n0 & 127], 0.0f);
        g = __fmaf_rn(s_W1[t], q[n1 & 127], g);
        g = __fmaf_rn(s_W2[t], q[n2 & 127], g);
        gate = g;
        uint32_t lr = s_lrc[t];
        int lt = lr & 127, rt2 = (lr >> 7) & 127;
        int dl = lt - ls; if (dl < 0) dl = -dl;
        int dr = rt2 - rs; if (dr < 0) dr = -dr;
        bool neq = (t != s);
        bool geom = neq && (dl <= 1) && (dr <= 1);
        unsigned long long bits = (ri0 & 64) ? ub1 : ub0;
        bool um = (((bits >> (ri0 & 63)) & 1ull) != 0) && ((lr >> 14) & 1u) && neq;
        valid = um || geom;
    };

    // Stage 3: scan; key = gate_bits<<32 | (NS - t)  (asc-index tie in fast path)
    unsigned long long top[NK2];
#pragma unroll
    for (int j = 0; j < NK2; ++j) top[j] = 0ull;

    for (int t0 = 0; t0 < NS; t0 += 64) {
        int t = t0 + lane;
        unsigned long long key = 0ull;
        if (t < NS) {
            float gate; bool valid;
            eval_gate(t, gate, valid);
            if (valid)
                key = ((unsigned long long)__float_as_uint(gate) << 32) | (uint32_t)(NS - t);
        }
#pragma unroll
        for (int j = 0; j < NK2; ++j) {
            unsigned long long a = top[j];
            unsigned long long mx = (a >= key) ? a : key;
            unsigned long long mn = (a >= key) ? key : a;
            top[j] = mx; key = mn;
        }
    }

    // Stage 4: merge to exact global top-11 (lanes 0..10 hold ranks 1..11)
    unsigned long long mine = 0ull;
    int p = 0;
    for (int j = 0; j < NK2; ++j) {
        unsigned long long c = (p < NK2) ? top[p] : 0ull;
        unsigned long long r = c;
#pragma unroll
        for (int off = 32; off > 0; off >>= 1) {
            unsigned long long o = __shfl_xor(r, off, 64);
            r = (o > r) ? o : r;
        }
        if (lane == j) mine = r;
        if (r == 0ull) break;
        if (c == r) ++p;
    }

    // Tie detect among ranks 1..11 (adjacent equal gate bits)
    bool flag;
    {
        unsigned long long nxt = __shfl_down(mine, 1, 64);
        bool tie = (lane < NK) && (mine != 0ull) && (nxt != 0ull) &&
                   ((mine >> 32) == (nxt >> 32));
        flag = (__ballot(tie) != 0ull);
    }
    if (lane == 0) s_flag[wid] = flag ? 1 : 0;

    if (lane < NK) {
        int o = (b * NS + s) * NK + lane;
        out[NB * NS * NK + o] = 1;                   // N_mask = ones always
        if (!flag) {
            int idx = (mine != 0ull) ? (NS - (int)(mine & 0xffffffffull)) : s;
            out[o] = idx;
        }
    }
    __syncthreads();

    // Slow path: exact numpy argsort(gate)[::-1][:K] for tie-flagged rows
    for (int w = 0; w < WPB; ++w) {
        if (s_flag[w] == 0) continue;                // block-uniform
        if (wid == w) {
            for (int t0 = 0; t0 < NS; t0 += 64) {
                int t = t0 + lane;
                if (t < NS) {
                    float gate; bool valid;
                    eval_gate(t, gate, valid);
                    unsigned hi32 = valid ? __float_as_uint(gate) : 0xFF800000u; // -inf
                    s_buf[t] = ((unsigned long long)hi32 << 32) | (unsigned)t;
                }
            }
        }
        __syncthreads();
        if (wid == w && lane == 0) np_introsort(s_buf, NS);
        __syncthreads();
        if (wid == w && lane < NK) {
            unsigned long long k = s_buf[NS - 1 - lane];  // reversed ascending
            int idx = ((unsigned)(k >> 32) == 0xFF800000u) ? s : (int)(k & 0xffffffffull);
            out[(b * NS + s) * NK + lane] = idx;
        }
        __syncthreads();
    }
}

extern "C" void kernel_launch(void* const* d_in, const int* in_sizes, int n_in,
                              void* d_out, int out_size, void* d_ws, size_t ws_size,
                              hipStream_t stream) {
    const int* hi = (const int*)d_in[0];
    const float* hw = (const float*)d_in[1];
    const float* dist = (const float*)d_in[2];
    int* out = (int*)d_out;

    unsigned char* ws = (unsigned char*)d_ws;
    unsigned char* top1 = ws;
    unsigned char* flags = ws + NB * NS;

    int n1 = NB * NS;
    top1_kernel<<<(n1 + 255) / 256, 256, 0, stream>>>(hi, top1, flags);
    cap_kernel<<<(NB * LL * 64) / 256, 256, 0, stream>>>(top1, flags);
    dim3 grid(NS / WPB, NB);
    span_topk_kernel<<<grid, 256, 0, stream>>>(hi, hw, dist, flags, out);
}

// Round 10
// 322.030 us; speedup vs baseline: 7.2966x; 7.2966x over previous
//
#include <hip/hip_runtime.h>
#include <stdint.h>

#define NB 8
#define LL 128
#define NS 1928      // number of spans (l,r), r-l+1 <= 16
#define NK 10        // top-k
#define NK2 11       // tracked depth (detect boundary ties at 10/11)
#define WPB 4        // waves (spans) per block

// span id for (l, r): offset(l) + (r-l)
__device__ __forceinline__ int span_id(int l, int r) {
    int off = (l <= 112) ? (l << 4) : (NS - (((128 - l) * (129 - l)) >> 1));
    return off + (r - l);
}

// Replica of numpy's SIMD float32 exp (verified exact vs oracle in R9).
__device__ __forceinline__ float npexp_f32(float x) {
    const float magic = 12582912.0f;
    const float log2e = 1.442695040888963f;
    const float c1 = -6.93145752e-1f;
    const float c2 = -1.42860677e-6f;
    float t = __fmul_rn(x, log2e);
    float q = __fsub_rn(__fadd_rn(t, magic), magic);
    float r = __fmaf_rn(q, c1, x);
    r = __fmaf_rn(q, c2, r);
    float num = __fmaf_rn(r, 5.082762527590693718096e-04f, 6.757896990527504603057e-03f);
    num = __fmaf_rn(num, r, 5.114512081637298353406e-02f);
    num = __fmaf_rn(num, r, 2.473615434895520810817e-01f);
    num = __fmaf_rn(num, r, 7.257664613233124478488e-01f);
    num = __fmaf_rn(num, r, 9.999999999980870924916e-01f);
    float den = __fmaf_rn(r, 2.159509375685829852307e-02f, -2.742335390411667452936e-01f);
    den = __fmaf_rn(den, r, 1.0f);
    float p = __fdiv_rn(num, den);
    int qi = (int)q;
    return __fmul_rn(p, __int_as_float((127 + qi) << 23));
}

__device__ __forceinline__ float keyval(unsigned long long k) {
    return __uint_as_float((unsigned)(k >> 32));
}

// intra-wave LDS ordering: compiler barrier + drain LDS ops
__device__ __forceinline__ void wfence() {
    __builtin_amdgcn_wave_barrier();
    __threadfence_block();
    __builtin_amdgcn_wave_barrier();
}

// r-th (0-based) set bit of m (m has > r set bits)
__device__ __forceinline__ int sel_bit(unsigned long long m, int r) {
    int pos = 0;
#pragma unroll
    for (int w = 32; w >= 1; w >>= 1) {
        int c = __popcll(m & ((1ull << w) - 1ull));
        if (r >= c) { r -= c; m >>= w; pos += w; }
    }
    return pos;
}

// Wave-parallel emulation of numpy aquicksort's partition step on a[pl..pr].
// Exactly reproduces the sequential median-of-3 + Hoare-scan outcome:
// swaps are pairs (L[k],R[k]) while L[k]<R[k]; pivot lands at min(L[K],R[K-1]).
__device__ int wave_partition(unsigned long long* a, int pl, int pr, int lane) {
    int pm = pl + ((pr - pl) >> 1);
    unsigned long long vl = a[pl], vm = a[pm], vr = a[pr], tt;
    if (keyval(vm) < keyval(vl)) { tt = vm; vm = vl; vl = tt; }
    if (keyval(vr) < keyval(vm)) { tt = vr; vr = vm; vm = tt; }
    if (keyval(vm) < keyval(vl)) { tt = vm; vm = vl; vl = tt; }
    float vp = keyval(vm);
    unsigned long long vq = a[pr - 1];
    if (lane == 0) { a[pl] = vl; a[pr] = vr; a[pm] = vq; a[pr - 1] = vm; }
    wfence();

    int n = pr - pl + 1;
    int nch = (n + 63) >> 6;
    unsigned long long mge = 0ull, mle = 0ull;   // lane c holds chunk c's masks
    for (int c = 0; c < nch; ++c) {
        int pos = pl + (c << 6) + lane;
        bool inr = (pos <= pr);
        float v = inr ? keyval(a[pos]) : 0.0f;
        bool ge = inr && (pos > pl) && (pos < pr) && (v >= vp);
        bool le = inr && (pos <= pr - 2) && (v <= vp);
        unsigned long long bge = __ballot(ge);
        unsigned long long ble = __ballot(le);
        if (lane == c) { mge = bge; mle = ble; }
    }
    int cge = __popcll(mge), cle = __popcll(mle);
    int ige = cge, ile = cle;                    // inclusive prefix over chunks
    for (int off = 1; off < 64; off <<= 1) {
        int xg = __shfl_up(ige, off, 64);
        int xl = __shfl_up(ile, off, 64);
        if (lane >= off) { ige += xg; ile += xl; }
    }
    int totGE = __shfl(ige, 63, 64);
    int totLE = __shfl(ile, 63, 64);
    int ege = ige - cge, ele = ile - cle;        // exclusive prefixes

    auto selL = [&](int k) -> int {              // k-th ge position, ascending
        int c = 0, e0 = 0;
        for (int cc = 0; cc < nch; ++cc) {
            int e = __shfl(ege, cc, 64);
            int cnt = __shfl(cge, cc, 64);
            if (k >= e && k < e + cnt) { c = cc; e0 = e; }
        }
        unsigned long long m = __shfl(mge, c, 64);
        return pl + (c << 6) + sel_bit(m, k - e0);
    };
    auto selR = [&](int k) -> int {              // k-th le position from the TOP
        int c = 0, r = 0;
        for (int cc = 0; cc < nch; ++cc) {
            int e = __shfl(ele, cc, 64);
            int cnt = __shfl(cle, cc, 64);
            int above = totLE - e - cnt;
            if (k >= above && k < above + cnt) { c = cc; r = cnt - 1 - (k - above); }
        }
        unsigned long long m = __shfl(mle, c, 64);
        return pl + (c << 6) + sel_bit(m, r);
    };

    int K = 0;
    int maxk = (totGE < totLE) ? totGE : totLE;
    for (int base = 0;; base += 64) {
        int k = base + lane;
        bool active = (k < maxk);
        int kq = active ? k : 0;
        int Lk = selL(kq);
        int Rk = selR(kq);
        bool sw = active && (Lk < Rk);
        unsigned long long bm = __ballot(sw);    // monotone prefix of true
        int nsw = (~bm == 0ull) ? 64 : (__ffsll((long long)~bm) - 1);
        if (sw && (lane < nsw)) {
            unsigned long long tl = a[Lk], tr = a[Rk];
            a[Lk] = tr; a[Rk] = tl;
        }
        K += nsw;
        if (nsw < 64) break;
    }
    wfence();
    int pi = selL(K);
    if (K > 0) { int rp = selR(K - 1); if (rp < pi) pi = rp; }
    if (lane == 0) { tt = a[pi]; a[pi] = a[pr - 1]; a[pr - 1] = tt; }
    wfence();
    return pi;
}

// numpy aheapsort sift (per-lane sequential, exact)
__device__ __forceinline__ void lane_sift(unsigned long long* h, int start, int hm) {
    unsigned long long tmp = h[start];
    int i = start, j = start + start;
    while (j <= hm) {
        if (j < hm && keyval(h[j]) < keyval(h[j + 1])) ++j;
        if (keyval(tmp) < keyval(h[j])) { h[i] = h[j]; i = j; j += j; }
        else break;
    }
    h[i] = tmp;
}

// numpy aheapsort on a[lo..hi], but only the extractions that finalize
// positions >= needlo (the rest of the heap is never read by the output).
// Build-heap is level-parallel (disjoint subtrees == sequential outcome).
__device__ void wave_heap_top(unsigned long long* a, int lo, int hi, int needlo, int lane) {
    unsigned long long* h = a + lo - 1;          // 1-based
    int hm = hi - lo + 1;
    int half = hm >> 1;
    int maxlvl = 0; { int v = half; while (v >>= 1) ++maxlvl; }
    for (int lvl = maxlvl; lvl >= 0; --lvl) {
        int n0 = 1 << lvl;
        int n1 = (n0 << 1) - 1; if (n1 > half) n1 = half;
        for (int nb = n0; nb <= n1; nb += 64) {
            int node = nb + lane;
            if (node <= n1) lane_sift(h, node, hm);
        }
        wfence();
    }
    int E = hi - needlo + 1;
    if (E > hm - 1) E = hm - 1;
    if (lane == 0) {
        int m = hm;
        for (int e = 0; e < E; ++e) {
            unsigned long long tmp = h[m]; h[m] = h[1]; --m;
            int i = 1, j = 2;
            while (j <= m) {
                if (j < m && keyval(h[j]) < keyval(h[j + 1])) ++j;
                if (keyval(tmp) < keyval(h[j])) { h[i] = h[j]; i = j; j += j; }
                else break;
            }
            h[i] = tmp;
        }
    }
    wfence();
}

// stable insertion-sort outcome via parallel stable rank (len <= 16)
__device__ void wave_insertion(unsigned long long* a, int lo, int hi, int lane) {
    int len = hi - lo + 1;
    unsigned long long v = (lane < len) ? a[lo + lane] : 0ull;
    float fv = keyval(v);
    int rank = 0;
    for (int j = 0; j < len; ++j) {
        unsigned long long vj = __shfl(v, j, 64);
        float fj = keyval(vj);
        if ((fj < fv) || (fj == fv && j < lane)) ++rank;
    }
    wfence();
    if (lane < len) a[lo + rank] = v;
    wfence();
}

// numpy introsort (R9-verified semantics: GLOBAL depth budget, SMALL=15,
// push-larger/continue-smaller), computing only positions >= n-NK exactly.
__device__ void wave_np_sort_top(unsigned long long* a, int n, int lane, int* stk) {
    int depth = 0; { int v = n; while (v >>= 1) ++depth; }
    depth *= 2;
    const int TOPLO = n - NK;
    int sp = 0;
    int lo = 0, hi = n - 1;
    for (;;) {
        while (hi - lo > 15) {
            if (depth-- < 0) {
                if (hi >= TOPLO) wave_heap_top(a, lo, hi, (lo > TOPLO ? lo : TOPLO), lane);
                goto pop;
            }
            {
                int pi = wave_partition(a, lo, hi, lane);
                if (pi - lo < hi - pi) {
                    if (lane == 0) { stk[sp * 2] = pi + 1; stk[sp * 2 + 1] = hi; }
                    ++sp; hi = pi - 1;
                } else {
                    if (lane == 0) { stk[sp * 2] = lo; stk[sp * 2 + 1] = pi - 1; }
                    ++sp; lo = pi + 1;
                }
                wfence();
            }
        }
        if (hi > lo && hi >= TOPLO) wave_insertion(a, lo, hi, lane);
pop:
        if (sp == 0) break;
        --sp;
        lo = stk[sp * 2]; hi = stk[sp * 2 + 1];
    }
}

// Kernel 1: per (b,t) extract raw top1 head index, zero flags
__global__ void top1_kernel(const int* __restrict__ hi,
                            unsigned char* __restrict__ top1,
                            unsigned char* __restrict__ flags) {
    int tid = blockIdx.x * blockDim.x + threadIdx.x;
    if (tid >= NB * NS) return;
    int b = tid / NS, t = tid - b * NS;
    int l, r;
    if (t < 1808) { l = t >> 4; r = l + (t & 15); }
    else {
        l = 113;
        while (l < 127 && span_id(l + 1, l + 1) <= t) ++l;
        r = l + (t - span_id(l, l));
    }
    int i0 = hi[((b * LL + l) * LL + r) * 4];
    top1[b * NS + t] = (unsigned char)(i0 & 127);
    flags[b * NS + t] = 0;
}

// Kernel 2: one wave per (b,l) — cumsum cap: keep first 128 spans (t order) with top1==l
__global__ void cap_kernel(const unsigned char* __restrict__ top1,
                           unsigned char* __restrict__ flags) {
    int gw = (blockIdx.x * blockDim.x + threadIdx.x) >> 6;
    int lane = threadIdx.x & 63;
    int b = gw >> 7, l = gw & 127;
    const unsigned char* tb = top1 + b * NS;
    unsigned char* fb = flags + b * NS;
    int cnt = 0;
    for (int t0 = 0; t0 < NS; t0 += 64) {
        int t = t0 + lane;
        int tp = (t < NS) ? (int)tb[t] : 255;
        bool match = (tp == l);
        unsigned long long m = __ballot(match);
        if (match) {
            int pre = __popcll(m & ((1ull << lane) - 1ull));
            fb[t] = (cnt + pre + 1 <= 128) ? 1 : 0;
        }
        cnt += __popcll(m);
    }
}

// Kernel 3: main — one wave per span s; tie-aware with exact numpy-argsort slow path
__global__ __launch_bounds__(256)
void span_topk_kernel(const int* __restrict__ hi, const float* __restrict__ hw,
                      const float* __restrict__ dist,
                      const unsigned char* __restrict__ flags,
                      int* __restrict__ out) {
    __shared__ uint32_t s_rec[NS];
    __shared__ float s_W0[NS], s_W1[NS], s_W2[NS];
    __shared__ uint16_t s_lrc[NS];
    __shared__ float s_q[WPB][LL];
    __shared__ unsigned long long s_buf[NS];   // slow-path packed sort keys
    __shared__ int s_flag[WPB];
    __shared__ int s_stk[48];                  // introsort segment stack (<=21 pushes)

    const int b = blockIdx.y;
    const int* hb = hi + b * LL * LL * 4;
    const float* wb = hw + b * LL * LL * 4;
    const unsigned char* fb = flags + b * NS;

    // Stage 1: per-batch candidate table; heads sorted by index, duplicates combined in k-order
    for (int j = threadIdx.x; j < LL * 16; j += 256) {
        int l = j >> 4, w = j & 15, r = l + w;
        if (r < LL) {
            int sid = span_id(l, r);
            int4 iv = *(const int4*)(hb + (l * LL + r) * 4);
            float4 wv = *(const float4*)(wb + (l * LL + r) * 4);
            int ia = iv.x, ib = iv.y, ic = iv.z;
            float wa = wv.x, wb2 = wv.y, wc = wv.z;
            int m0, m1 = 255, m2 = 255;
            float W0, W1 = 0.f, W2 = 0.f;
            if (ia == ib && ib == ic) {
                m0 = ia; W0 = __fadd_rn(__fadd_rn(wa, wb2), wc);
            } else if (ia == ib) {
                float W = __fadd_rn(wa, wb2);
                if (ia < ic) { m0 = ia; W0 = W; m1 = ic; W1 = wc; }
                else         { m0 = ic; W0 = wc; m1 = ia; W1 = W; }
            } else if (ia == ic) {
                float W = __fadd_rn(wa, wc);
                if (ia < ib) { m0 = ia; W0 = W; m1 = ib; W1 = wb2; }
                else         { m0 = ib; W0 = wb2; m1 = ia; W1 = W; }
            } else if (ib == ic) {
                float W = __fadd_rn(wb2, wc);
                if (ia < ib) { m0 = ia; W0 = wa; m1 = ib; W1 = W; }
                else         { m0 = ib; W0 = W; m1 = ia; W1 = wa; }
            } else {
                int x0 = ia, x1 = ib, x2 = ic; float y0 = wa, y1 = wb2, y2 = wc;
                if (x0 > x1) { int tx = x0; x0 = x1; x1 = tx; float ty = y0; y0 = y1; y1 = ty; }
                if (x1 > x2) { int tx = x1; x1 = x2; x2 = tx; float ty = y1; y1 = y2; y2 = ty; }
                if (x0 > x1) { int tx = x0; x0 = x1; x1 = tx; float ty = y0; y0 = y1; y1 = ty; }
                m0 = x0; m1 = x1; m2 = x2; W0 = y0; W1 = y1; W2 = y2;
            }
            uint32_t cap = fb[sid] & 1u;
            s_rec[sid] = (uint32_t)m0 | ((uint32_t)m1 << 8) | ((uint32_t)m2 << 16)
                       | ((uint32_t)(ia & 127) << 24);
            s_W0[sid] = W0; s_W1[sid] = W1; s_W2[sid] = W2;
            s_lrc[sid] = (uint16_t)(l | (r << 7) | (cap << 14));
        }
    }
    __syncthreads();

    const int wid = threadIdx.x >> 6;
    const int lane = threadIdx.x & 63;
    const int s = blockIdx.x * WPB + wid;

    // Stage 2: q row (ascending-index FMA chain from 0) + coverage ballots
    uint32_t rec = s_rec[s];
    int m0 = rec & 255, m1 = (rec >> 8) & 255, m2 = (rec >> 16) & 255;
    bool e1 = (m1 != 255), e2 = (m2 != 255);
    float W0 = s_W0[s], W1 = s_W1[s], W2 = s_W2[s];
    uint32_t lrc = s_lrc[s];
    int ls = lrc & 127, rs = (lrc >> 7) & 127;

    const float* db = dist + b * LL * LL;
    const float* row0 = db + m0 * LL;
    const float* row1 = db + (e1 ? m1 : 0) * LL;
    const float* row2 = db + (e2 ? m2 : 0) * LL;
    int mA = lane, mB = lane + 64;
    float dA0 = row0[mA], dB0 = row0[mB];
    float dA1 = row1[mA], dB1 = row1[mB];
    float dA2 = row2[mA], dB2 = row2[mB];
    float qA = __fmaf_rn(W0, npexp_f32(-dA0), 0.0f);
    qA = __fmaf_rn(W1, npexp_f32(-dA1), qA);
    qA = __fmaf_rn(W2, npexp_f32(-dA2), qA);
    float qB = __fmaf_rn(W0, npexp_f32(-dB0), 0.0f);
    qB = __fmaf_rn(W1, npexp_f32(-dB1), qB);
    qB = __fmaf_rn(W2, npexp_f32(-dB2), qB);
    bool cA = (dA0 <= 2.0f || mA == m0) ||
              (e1 && (dA1 <= 2.0f || mA == m1)) ||
              (e2 && (dA2 <= 2.0f || mA == m2));
    bool cB = (dB0 <= 2.0f || mB == m0) ||
              (e1 && (dB1 <= 2.0f || mB == m1)) ||
              (e2 && (dB2 <= 2.0f || mB == m2));
    unsigned long long ub0 = __ballot(cA);
    unsigned long long ub1 = __ballot(cB);
    s_q[wid][mA] = qA;
    s_q[wid][mB] = qB;

    const float* q = s_q[wid];

    // shared gate+mask evaluator: used by BOTH fast scan and slow path (bit-identical)
    auto eval_gate = [&](int t, float& gate, bool& valid) {
        uint32_t rt = s_rec[t];
        int n0 = rt & 255, n1 = (rt >> 8) & 255, n2 = (rt >> 16) & 255, ri0 = rt >> 24;
        float g = __fmaf_rn(s_W0[t], q[n0 & 127], 0.0f);
        g = __fmaf_rn(s_W1[t], q[n1 & 127], g);
        g = __fmaf_rn(s_W2[t], q[n2 & 127], g);
        gate = g;
        uint32_t lr = s_lrc[t];
        int lt = lr & 127, rt2 = (lr >> 7) & 127;
        int dl = lt - ls; if (dl < 0) dl = -dl;
        int dr = rt2 - rs; if (dr < 0) dr = -dr;
        bool neq = (t != s);
        bool geom = neq && (dl <= 1) && (dr <= 1);
        unsigned long long bits = (ri0 & 64) ? ub1 : ub0;
        bool um = (((bits >> (ri0 & 63)) & 1ull) != 0) && ((lr >> 14) & 1u) && neq;
        valid = um || geom;
    };

    // Stage 3: scan; key = gate_bits<<32 | (NS - t)
    unsigned long long top[NK2];
#pragma unroll
    for (int j = 0; j < NK2; ++j) top[j] = 0ull;

    for (int t0 = 0; t0 < NS; t0 += 64) {
        int t = t0 + lane;
        unsigned long long key = 0ull;
        if (t < NS) {
            float gate; bool valid;
            eval_gate(t, gate, valid);
            if (valid)
                key = ((unsigned long long)__float_as_uint(gate) << 32) | (uint32_t)(NS - t);
        }
#pragma unroll
        for (int j = 0; j < NK2; ++j) {
            unsigned long long a = top[j];
            unsigned long long mx = (a >= key) ? a : key;
            unsigned long long mn = (a >= key) ? key : a;
            top[j] = mx; key = mn;
        }
    }

    // Stage 4: merge to exact global top-11 (lanes 0..10 hold ranks 1..11)
    unsigned long long mine = 0ull;
    int p = 0;
    for (int j = 0; j < NK2; ++j) {
        unsigned long long c = (p < NK2) ? top[p] : 0ull;
        unsigned long long r = c;
#pragma unroll
        for (int off = 32; off > 0; off >>= 1) {
            unsigned long long o = __shfl_xor(r, off, 64);
            r = (o > r) ? o : r;
        }
        if (lane == j) mine = r;
        if (r == 0ull) break;
        if (c == r) ++p;
    }

    // Tie detect among ranks 1..11 (adjacent equal gate bits)
    bool flag;
    {
        unsigned long long nxt = __shfl_down(mine, 1, 64);
        bool tie = (lane < NK) && (mine != 0ull) && (nxt != 0ull) &&
                   ((mine >> 32) == (nxt >> 32));
        flag = (__ballot(tie) != 0ull);
    }
    if (lane == 0) s_flag[wid] = flag ? 1 : 0;

    if (lane < NK) {
        int o = (b * NS + s) * NK + lane;
        out[NB * NS * NK + o] = 1;                   // N_mask = ones always
        if (!flag) {
            int idx = (mine != 0ull) ? (NS - (int)(mine & 0xffffffffull)) : s;
            out[o] = idx;
        }
    }
    __syncthreads();

    // Slow path: exact numpy argsort(gate)[::-1][:K] for tie-flagged rows,
    // computed with the wave-parallel top-only introsort emulation.
    for (int w = 0; w < WPB; ++w) {
        if (s_flag[w] == 0) continue;                // block-uniform
        if (wid == w) {
            for (int t0 = 0; t0 < NS; t0 += 64) {
                int t = t0 + lane;
                if (t < NS) {
                    float gate; bool valid;
                    eval_gate(t, gate, valid);
                    unsigned h32 = valid ? __float_as_uint(gate) : 0xFF800000u; // -inf
                    s_buf[t] = ((unsigned long long)h32 << 32) | (unsigned)t;
                }
            }
        }
        __syncthreads();
        if (wid == w) wave_np_sort_top(s_buf, NS, lane, s_stk);
        __syncthreads();
        if (wid == w && lane < NK) {
            unsigned long long k = s_buf[NS - 1 - lane];  // reversed ascending
            int idx = ((unsigned)(k >> 32) == 0xFF800000u) ? s : (int)(k & 0xffffffffull);
            out[(b * NS + s) * NK + lane] = idx;
        }
        __syncthreads();
    }
}

extern "C" void kernel_launch(void* const* d_in, const int* in_sizes, int n_in,
                              void* d_out, int out_size, void* d_ws, size_t ws_size,
                              hipStream_t stream) {
    const int* hi = (const int*)d_in[0];
    const float* hw = (const float*)d_in[1];
    const float* dist = (const float*)d_in[2];
    int* out = (int*)d_out;

    unsigned char* ws = (unsigned char*)d_ws;
    unsigned char* top1 = ws;
    unsigned char* flags = ws + NB * NS;

    int n1 = NB * NS;
    top1_kernel<<<(n1 + 255) / 256, 256, 0, stream>>>(hi, top1, flags);
    cap_kernel<<<(NB * LL * 64) / 256, 256, 0, stream>>>(top1, flags);
    dim3 grid(NS / WPB, NB);
    span_topk_kernel<<<grid, 256, 0, stream>>>(hi, hw, dist, flags, out);
}